// Round 12
// baseline (877.737 us; speedup 1.0000x reference)
//
#include <hip/hip_runtime.h>
#include <stdint.h>

#define N_ELEM 16777216
#define N_PAIR (N_ELEM / 2)
#define NUM_SEG 1000000
#define NXCD 8

typedef int   int4v   __attribute__((ext_vector_type(4)));
typedef float float2v __attribute__((ext_vector_type(2)));
typedef float float4v __attribute__((ext_vector_type(4)));
typedef unsigned int uint4v __attribute__((ext_vector_type(4)));

// ---------- common ----------

__device__ __forceinline__ unsigned int xcc_id() {
    // s_getreg_b32 hwreg(HW_REG_XCC_ID=20, offset=0, width=32) [m09-verified]
    return (unsigned int)__builtin_amdgcn_s_getreg((31u << 11) | 20u) & 7u;
}

__global__ void gtsms_zero_kernel(uint4v* __restrict__ ws, int n_vec4) {
    int i = blockIdx.x * blockDim.x + threadIdx.x;
    if (i < n_vec4) ws[i] = (uint4v){0u, 0u, 0u, 0u};
}

// Gather from 4 MB read-only bf16 tables; 4 elements/thread.
__global__ void gtsms_gather_kernel(const int* __restrict__ pp,
                                    const unsigned short* __restrict__ mb0,
                                    const unsigned short* __restrict__ mb1,
                                    float* __restrict__ out) {
    int t = blockIdx.x * blockDim.x + threadIdx.x;
    if (t < N_PAIR / 2) {
        int p = 2 * t;
        int4v prA = __builtin_nontemporal_load(reinterpret_cast<const int4v*>(pp) + p);
        int4v prB = __builtin_nontemporal_load(reinterpret_cast<const int4v*>(pp) + p + 1);
        unsigned int a0 = mb0[prA.x];
        unsigned int b0 = mb1[prA.y];
        unsigned int a1 = mb0[prA.z];
        unsigned int b1 = mb1[prA.w];
        unsigned int a2 = mb0[prB.x];
        unsigned int b2 = mb1[prB.y];
        unsigned int a3 = mb0[prB.z];
        unsigned int b3 = mb1[prB.w];
        float4v o;
        o.x = __uint_as_float(a0 << 16) * __uint_as_float(b0 << 16);
        o.y = __uint_as_float(a1 << 16) * __uint_as_float(b1 << 16);
        o.z = __uint_as_float(a2 << 16) * __uint_as_float(b2 << 16);
        o.w = __uint_as_float(a3 << 16) * __uint_as_float(b3 << 16);
        __builtin_nontemporal_store(o, reinterpret_cast<float4v*>(out) + t);
    }
}

// ---------- replica (fast) path ----------
// ws: [rep: NXCD * 2 * 1M u32 = 64 MB][mb0: 1M u16][mb1: 1M u16] = 68 MB.
// Each XCD atomically maxes into its OWN replica at workgroup scope ->
// RMW executes at the XCD's local TCC (atomic for all CUs of that XCD;
// no cross-XCD address sharing by construction). Kernel-end release
// flushes dirty L2, so the refresh/merge kernels see committed values.

__global__ void gtsms_scatter_rep(const int* __restrict__ pp,
                                  const float* __restrict__ feat,
                                  unsigned int* __restrict__ rep,
                                  const unsigned short* __restrict__ mb0,
                                  const unsigned short* __restrict__ mb1,
                                  int base_pair, int n_threads) {
    unsigned int* r0 = rep + (size_t)xcc_id() * (2 * NUM_SEG);
    unsigned int* r1 = r0 + NUM_SEG;
    int t = blockIdx.x * blockDim.x + threadIdx.x;
    if (t >= n_threads) return;
    int p = base_pair + 2 * t;
    int4v prA = __builtin_nontemporal_load(reinterpret_cast<const int4v*>(pp) + p);
    int4v prB = __builtin_nontemporal_load(reinterpret_cast<const int4v*>(pp) + p + 1);
    float2v fvA = __builtin_nontemporal_load(reinterpret_cast<const float2v*>(feat) + p);
    float2v fvB = __builtin_nontemporal_load(reinterpret_cast<const float2v*>(feat) + p + 1);
    unsigned int f0 = __float_as_uint(fvA.x);
    unsigned int f1 = __float_as_uint(fvA.y);
    unsigned int f2 = __float_as_uint(fvB.x);
    unsigned int f3 = __float_as_uint(fvB.y);
    unsigned int c0 = mb0[prA.x];
    unsigned int c1 = mb1[prA.y];
    unsigned int c2 = mb0[prA.z];
    unsigned int c3 = mb1[prA.w];
    unsigned int c4 = mb0[prB.x];
    unsigned int c5 = mb1[prB.y];
    unsigned int c6 = mb0[prB.z];
    unsigned int c7 = mb1[prB.w];
    if (f0 > (c0 << 16)) __hip_atomic_fetch_max(&r0[prA.x], f0, __ATOMIC_RELAXED, __HIP_MEMORY_SCOPE_WORKGROUP);
    if (f0 > (c1 << 16)) __hip_atomic_fetch_max(&r1[prA.y], f0, __ATOMIC_RELAXED, __HIP_MEMORY_SCOPE_WORKGROUP);
    if (f1 > (c2 << 16)) __hip_atomic_fetch_max(&r0[prA.z], f1, __ATOMIC_RELAXED, __HIP_MEMORY_SCOPE_WORKGROUP);
    if (f1 > (c3 << 16)) __hip_atomic_fetch_max(&r1[prA.w], f1, __ATOMIC_RELAXED, __HIP_MEMORY_SCOPE_WORKGROUP);
    if (f2 > (c4 << 16)) __hip_atomic_fetch_max(&r0[prB.x], f2, __ATOMIC_RELAXED, __HIP_MEMORY_SCOPE_WORKGROUP);
    if (f2 > (c5 << 16)) __hip_atomic_fetch_max(&r1[prB.y], f2, __ATOMIC_RELAXED, __HIP_MEMORY_SCOPE_WORKGROUP);
    if (f3 > (c6 << 16)) __hip_atomic_fetch_max(&r0[prB.z], f3, __ATOMIC_RELAXED, __HIP_MEMORY_SCOPE_WORKGROUP);
    if (f3 > (c7 << 16)) __hip_atomic_fetch_max(&r1[prB.w], f3, __ATOMIC_RELAXED, __HIP_MEMORY_SCOPE_WORKGROUP);
}

// Merge 8 replicas -> trunc16 mirror (filter refresh; conservative lower bound).
__global__ void gtsms_refresh_rep(const unsigned int* __restrict__ rep,
                                  unsigned short* __restrict__ mb0,
                                  unsigned short* __restrict__ mb1) {
    int i = blockIdx.x * blockDim.x + threadIdx.x;
    if (i < NUM_SEG) {
        unsigned int u0 = 0u, u1 = 0u;
#pragma unroll
        for (int x = 0; x < NXCD; ++x) {
            u0 = max(u0, rep[(size_t)x * (2 * NUM_SEG) + i]);
            u1 = max(u1, rep[(size_t)x * (2 * NUM_SEG) + NUM_SEG + i]);
        }
        mb0[i] = (unsigned short)(u0 >> 16);
        mb1[i] = (unsigned short)(u1 >> 16);
    }
}

// Merge 8 replicas -> RTNE bf16 tables for the gather.
__global__ void gtsms_merge_rtne_rep(const unsigned int* __restrict__ rep,
                                     unsigned short* __restrict__ mb0,
                                     unsigned short* __restrict__ mb1) {
    int i = blockIdx.x * blockDim.x + threadIdx.x;
    if (i < NUM_SEG) {
        unsigned int u0 = 0u, u1 = 0u;
#pragma unroll
        for (int x = 0; x < NXCD; ++x) {
            u0 = max(u0, rep[(size_t)x * (2 * NUM_SEG) + i]);
            u1 = max(u1, rep[(size_t)x * (2 * NUM_SEG) + NUM_SEG + i]);
        }
        mb0[i] = (unsigned short)((u0 + 0x7FFFu + ((u0 >> 16) & 1u)) >> 16);
        mb1[i] = (unsigned short)((u1 + 0x7FFFu + ((u1 >> 16) & 1u)) >> 16);
    }
}

// ---------- fallback (R9) path: device-scope atomics on single tables ----------

__global__ void gtsms_scatter_chunk(const int* __restrict__ pp,
                                    const float* __restrict__ feat,
                                    unsigned int* __restrict__ m0,
                                    unsigned int* __restrict__ m1,
                                    const unsigned short* __restrict__ mb0,
                                    const unsigned short* __restrict__ mb1,
                                    int base_pair, int n_threads) {
    int t = blockIdx.x * blockDim.x + threadIdx.x;
    if (t >= n_threads) return;
    int p = base_pair + 2 * t;
    int4v prA = __builtin_nontemporal_load(reinterpret_cast<const int4v*>(pp) + p);
    int4v prB = __builtin_nontemporal_load(reinterpret_cast<const int4v*>(pp) + p + 1);
    float2v fvA = __builtin_nontemporal_load(reinterpret_cast<const float2v*>(feat) + p);
    float2v fvB = __builtin_nontemporal_load(reinterpret_cast<const float2v*>(feat) + p + 1);
    unsigned int f0 = __float_as_uint(fvA.x);
    unsigned int f1 = __float_as_uint(fvA.y);
    unsigned int f2 = __float_as_uint(fvB.x);
    unsigned int f3 = __float_as_uint(fvB.y);
    unsigned int c0 = mb0[prA.x];
    unsigned int c1 = mb1[prA.y];
    unsigned int c2 = mb0[prA.z];
    unsigned int c3 = mb1[prA.w];
    unsigned int c4 = mb0[prB.x];
    unsigned int c5 = mb1[prB.y];
    unsigned int c6 = mb0[prB.z];
    unsigned int c7 = mb1[prB.w];
    if (f0 > (c0 << 16)) atomicMax(&m0[prA.x], f0);
    if (f0 > (c1 << 16)) atomicMax(&m1[prA.y], f0);
    if (f1 > (c2 << 16)) atomicMax(&m0[prA.z], f1);
    if (f1 > (c3 << 16)) atomicMax(&m1[prA.w], f1);
    if (f2 > (c4 << 16)) atomicMax(&m0[prB.x], f2);
    if (f2 > (c5 << 16)) atomicMax(&m1[prB.y], f2);
    if (f3 > (c6 << 16)) atomicMax(&m0[prB.z], f3);
    if (f3 > (c7 << 16)) atomicMax(&m1[prB.w], f3);
}

__global__ void gtsms_refresh_kernel(const unsigned int* __restrict__ m0,
                                     const unsigned int* __restrict__ m1,
                                     unsigned short* __restrict__ mb0,
                                     unsigned short* __restrict__ mb1) {
    int i = blockIdx.x * blockDim.x + threadIdx.x;
    if (i < NUM_SEG) {
        mb0[i] = (unsigned short)(m0[i] >> 16);
        mb1[i] = (unsigned short)(m1[i] >> 16);
    }
}

__global__ void gtsms_convert_rtne_kernel(const unsigned int* __restrict__ m0,
                                          const unsigned int* __restrict__ m1,
                                          unsigned short* __restrict__ mb0,
                                          unsigned short* __restrict__ mb1) {
    int i = blockIdx.x * blockDim.x + threadIdx.x;
    if (i < NUM_SEG) {
        unsigned int u0 = m0[i];
        unsigned int u1 = m1[i];
        mb0[i] = (unsigned short)((u0 + 0x7FFFu + ((u0 >> 16) & 1u)) >> 16);
        mb1[i] = (unsigned short)((u1 + 0x7FFFu + ((u1 >> 16) & 1u)) >> 16);
    }
}

// ---------- launch ----------

extern "C" void kernel_launch(void* const* d_in, const int* in_sizes, int n_in,
                              void* d_out, int out_size, void* d_ws, size_t ws_size,
                              hipStream_t stream) {
    const int* pp = (const int*)d_in[0];          // (N,2) int32, row-major
    const float* feat = (const float*)d_in[1];    // (N,) float32
    float* out = (float*)d_out;                   // (N,) float32

    const int BLK = 256;
    dim3 segGrid((NUM_SEG + BLK - 1) / BLK);
    dim3 gatherGrid((N_PAIR / 2 + BLK - 1) / BLK);

    const size_t REP_BYTES = (size_t)NXCD * 2 * NUM_SEG * 4;   // 64 MB
    const size_t MIR_BYTES = (size_t)2 * NUM_SEG * 2;          // 4 MB
    const bool use_rep = ws_size >= REP_BYTES + MIR_BYTES;

    // Chunk boundaries (pairs): sizes 1/64, 3/64, 1/16, 1/8, 1/4, 1/2.
    const int cb[7] = {0, N_PAIR / 64, N_PAIR / 16, N_PAIR / 8,
                       N_PAIR / 4, N_PAIR / 2, N_PAIR};

    if (use_rep) {
        unsigned int* rep = (unsigned int*)d_ws;                     // 16M u32
        unsigned short* mb0 = (unsigned short*)((char*)d_ws + REP_BYTES); // 1M u16
        unsigned short* mb1 = mb0 + NUM_SEG;                         // 1M u16

        int zero_vec4 = (int)((REP_BYTES + MIR_BYTES) / 16);
        dim3 zeroGrid((zero_vec4 + BLK - 1) / BLK);
        gtsms_zero_kernel<<<zeroGrid, BLK, 0, stream>>>((uint4v*)d_ws, zero_vec4);

        for (int c = 0; c < 6; ++c) {
            int n_threads = (cb[c + 1] - cb[c]) / 2;   // 2 pairs per thread
            dim3 g((n_threads + BLK - 1) / BLK);
            gtsms_scatter_rep<<<g, BLK, 0, stream>>>(pp, feat, rep, mb0, mb1,
                                                     cb[c], n_threads);
            if (c < 5)
                gtsms_refresh_rep<<<segGrid, BLK, 0, stream>>>(rep, mb0, mb1);
        }
        gtsms_merge_rtne_rep<<<segGrid, BLK, 0, stream>>>(rep, mb0, mb1);
        gtsms_gather_kernel<<<gatherGrid, BLK, 0, stream>>>(pp, mb0, mb1, out);
    } else {
        unsigned int* m0 = (unsigned int*)d_ws;                // 1M u32
        unsigned int* m1 = m0 + NUM_SEG;                       // 1M u32
        unsigned short* mb0 = (unsigned short*)(m1 + NUM_SEG); // 1M u16
        unsigned short* mb1 = mb0 + NUM_SEG;                   // 1M u16

        int zero_vec4 = (3 * NUM_SEG) / 4;
        dim3 zeroGrid((zero_vec4 + BLK - 1) / BLK);
        gtsms_zero_kernel<<<zeroGrid, BLK, 0, stream>>>((uint4v*)d_ws, zero_vec4);

        for (int c = 0; c < 6; ++c) {
            int n_threads = (cb[c + 1] - cb[c]) / 2;
            dim3 g((n_threads + BLK - 1) / BLK);
            gtsms_scatter_chunk<<<g, BLK, 0, stream>>>(pp, feat, m0, m1, mb0, mb1,
                                                       cb[c], n_threads);
            if (c < 5)
                gtsms_refresh_kernel<<<segGrid, BLK, 0, stream>>>(m0, m1, mb0, mb1);
        }
        gtsms_convert_rtne_kernel<<<segGrid, BLK, 0, stream>>>(m0, m1, mb0, mb1);
        gtsms_gather_kernel<<<gatherGrid, BLK, 0, stream>>>(pp, mb0, mb1, out);
    }
}

// Round 13
// 858.084 us; speedup vs baseline: 1.0229x; 1.0229x over previous
//
#include <hip/hip_runtime.h>
#include <stdint.h>

#define N_ELEM 16777216
#define N_PAIR (N_ELEM / 2)
#define NUM_SEG 1000000

typedef int   int4v   __attribute__((ext_vector_type(4)));
typedef float float2v __attribute__((ext_vector_type(2)));
typedef float float4v __attribute__((ext_vector_type(4)));
typedef unsigned int uint4v __attribute__((ext_vector_type(4)));

// L1-bypassing 2-byte load (sc0/sc1 -> serviced from L2, frees L1 MSHRs).
__device__ __forceinline__ unsigned int ld_u16_bypass(const unsigned short* p) {
    return (unsigned int)__hip_atomic_load((const unsigned short*)p,
                                           __ATOMIC_RELAXED,
                                           __HIP_MEMORY_SCOPE_AGENT);
}

// ws layout: [m0: 1M u32][m1: 1M u32][mb0: 1M u16][mb1: 1M u16] = 12 MB.
// m0/m1: exact f32-bit max tables (device-scope atomics, memory-side).
// mb0/mb1: bf16 mirror, READ-ONLY within each scatter chunk; refreshed
// between chunks (one-chunk-stale dynamic filter -> near-harmonic atomics).
// Mirror value = trunc16(committed exact value) <= true final max, so
// skipping f <= mirror<<16 never drops the true max. Exact stays exact.

__global__ void gtsms_zero_kernel(uint4v* __restrict__ ws, int n_vec4) {
    int i = blockIdx.x * blockDim.x + threadIdx.x;
    if (i < n_vec4) ws[i] = (uint4v){0u, 0u, 0u, 0u};
}

__global__ void gtsms_scatter_chunk(const int* __restrict__ pp,
                                    const float* __restrict__ feat,
                                    unsigned int* __restrict__ m0,
                                    unsigned int* __restrict__ m1,
                                    const unsigned short* __restrict__ mb0,
                                    const unsigned short* __restrict__ mb1,
                                    int base_pair, int n_threads) {
    int t = blockIdx.x * blockDim.x + threadIdx.x;
    if (t >= n_threads) return;
    int p = base_pair + 2 * t;
    int4v prA = __builtin_nontemporal_load(reinterpret_cast<const int4v*>(pp) + p);
    int4v prB = __builtin_nontemporal_load(reinterpret_cast<const int4v*>(pp) + p + 1);
    float2v fvA = __builtin_nontemporal_load(reinterpret_cast<const float2v*>(feat) + p);
    float2v fvB = __builtin_nontemporal_load(reinterpret_cast<const float2v*>(feat) + p + 1);
    unsigned int f0 = __float_as_uint(fvA.x);
    unsigned int f1 = __float_as_uint(fvA.y);
    unsigned int f2 = __float_as_uint(fvB.x);
    unsigned int f3 = __float_as_uint(fvB.y);
    // 8 independent L1-bypassing filter reads in flight
    unsigned int c0 = ld_u16_bypass(&mb0[prA.x]);
    unsigned int c1 = ld_u16_bypass(&mb1[prA.y]);
    unsigned int c2 = ld_u16_bypass(&mb0[prA.z]);
    unsigned int c3 = ld_u16_bypass(&mb1[prA.w]);
    unsigned int c4 = ld_u16_bypass(&mb0[prB.x]);
    unsigned int c5 = ld_u16_bypass(&mb1[prB.y]);
    unsigned int c6 = ld_u16_bypass(&mb0[prB.z]);
    unsigned int c7 = ld_u16_bypass(&mb1[prB.w]);
    if (f0 > (c0 << 16)) atomicMax(&m0[prA.x], f0);
    if (f0 > (c1 << 16)) atomicMax(&m1[prA.y], f0);
    if (f1 > (c2 << 16)) atomicMax(&m0[prA.z], f1);
    if (f1 > (c3 << 16)) atomicMax(&m1[prA.w], f1);
    if (f2 > (c4 << 16)) atomicMax(&m0[prB.x], f2);
    if (f2 > (c5 << 16)) atomicMax(&m1[prB.y], f2);
    if (f3 > (c6 << 16)) atomicMax(&m0[prB.z], f3);
    if (f3 > (c7 << 16)) atomicMax(&m1[prB.w], f3);
}

// Refresh mirror = trunc16(exact) — conservative lower bound.
__global__ void gtsms_refresh_kernel(const unsigned int* __restrict__ m0,
                                     const unsigned int* __restrict__ m1,
                                     unsigned short* __restrict__ mb0,
                                     unsigned short* __restrict__ mb1) {
    int i = blockIdx.x * blockDim.x + threadIdx.x;
    if (i < NUM_SEG) {
        mb0[i] = (unsigned short)(m0[i] >> 16);
        mb1[i] = (unsigned short)(m1[i] >> 16);
    }
}

// Final: exact f32 tables -> RTNE bf16 tables for the gather.
__global__ void gtsms_convert_rtne_kernel(const unsigned int* __restrict__ m0,
                                          const unsigned int* __restrict__ m1,
                                          unsigned short* __restrict__ mb0,
                                          unsigned short* __restrict__ mb1) {
    int i = blockIdx.x * blockDim.x + threadIdx.x;
    if (i < NUM_SEG) {
        unsigned int u0 = m0[i];
        unsigned int u1 = m1[i];
        mb0[i] = (unsigned short)((u0 + 0x7FFFu + ((u0 >> 16) & 1u)) >> 16);
        mb1[i] = (unsigned short)((u1 + 0x7FFFu + ((u1 >> 16) & 1u)) >> 16);
    }
}

// Gather: 8 elements/thread, 16 L1-bypassing random loads in flight.
__global__ void gtsms_gather_kernel(const int* __restrict__ pp,
                                    const unsigned short* __restrict__ mb0,
                                    const unsigned short* __restrict__ mb1,
                                    float* __restrict__ out) {
    int t = blockIdx.x * blockDim.x + threadIdx.x;
    if (t < N_PAIR / 4) {
        int p = 4 * t;
        int4v prA = __builtin_nontemporal_load(reinterpret_cast<const int4v*>(pp) + p);
        int4v prB = __builtin_nontemporal_load(reinterpret_cast<const int4v*>(pp) + p + 1);
        int4v prC = __builtin_nontemporal_load(reinterpret_cast<const int4v*>(pp) + p + 2);
        int4v prD = __builtin_nontemporal_load(reinterpret_cast<const int4v*>(pp) + p + 3);
        unsigned int a0 = ld_u16_bypass(&mb0[prA.x]);
        unsigned int b0 = ld_u16_bypass(&mb1[prA.y]);
        unsigned int a1 = ld_u16_bypass(&mb0[prA.z]);
        unsigned int b1 = ld_u16_bypass(&mb1[prA.w]);
        unsigned int a2 = ld_u16_bypass(&mb0[prB.x]);
        unsigned int b2 = ld_u16_bypass(&mb1[prB.y]);
        unsigned int a3 = ld_u16_bypass(&mb0[prB.z]);
        unsigned int b3 = ld_u16_bypass(&mb1[prB.w]);
        unsigned int a4 = ld_u16_bypass(&mb0[prC.x]);
        unsigned int b4 = ld_u16_bypass(&mb1[prC.y]);
        unsigned int a5 = ld_u16_bypass(&mb0[prC.z]);
        unsigned int b5 = ld_u16_bypass(&mb1[prC.w]);
        unsigned int a6 = ld_u16_bypass(&mb0[prD.x]);
        unsigned int b6 = ld_u16_bypass(&mb1[prD.y]);
        unsigned int a7 = ld_u16_bypass(&mb0[prD.z]);
        unsigned int b7 = ld_u16_bypass(&mb1[prD.w]);
        float4v o0, o1;
        o0.x = __uint_as_float(a0 << 16) * __uint_as_float(b0 << 16);
        o0.y = __uint_as_float(a1 << 16) * __uint_as_float(b1 << 16);
        o0.z = __uint_as_float(a2 << 16) * __uint_as_float(b2 << 16);
        o0.w = __uint_as_float(a3 << 16) * __uint_as_float(b3 << 16);
        o1.x = __uint_as_float(a4 << 16) * __uint_as_float(b4 << 16);
        o1.y = __uint_as_float(a5 << 16) * __uint_as_float(b5 << 16);
        o1.z = __uint_as_float(a6 << 16) * __uint_as_float(b6 << 16);
        o1.w = __uint_as_float(a7 << 16) * __uint_as_float(b7 << 16);
        __builtin_nontemporal_store(o0, reinterpret_cast<float4v*>(out) + 2 * t);
        __builtin_nontemporal_store(o1, reinterpret_cast<float4v*>(out) + 2 * t + 1);
    }
}

extern "C" void kernel_launch(void* const* d_in, const int* in_sizes, int n_in,
                              void* d_out, int out_size, void* d_ws, size_t ws_size,
                              hipStream_t stream) {
    const int* pp = (const int*)d_in[0];          // (N,2) int32, row-major
    const float* feat = (const float*)d_in[1];    // (N,) float32
    float* out = (float*)d_out;                   // (N,) float32

    unsigned int* m0 = (unsigned int*)d_ws;                // 1M u32
    unsigned int* m1 = m0 + NUM_SEG;                       // 1M u32
    unsigned short* mb0 = (unsigned short*)(m1 + NUM_SEG); // 1M u16
    unsigned short* mb1 = mb0 + NUM_SEG;                   // 1M u16

    const int BLK = 256;
    dim3 segGrid((NUM_SEG + BLK - 1) / BLK);
    dim3 gatherGrid((N_PAIR / 4 + BLK - 1) / BLK);

    int zero_vec4 = (3 * NUM_SEG) / 4;                     // 12 MB
    dim3 zeroGrid((zero_vec4 + BLK - 1) / BLK);
    gtsms_zero_kernel<<<zeroGrid, BLK, 0, stream>>>((uint4v*)d_ws, zero_vec4);

    // Chunk boundaries (pairs): sizes 1/64, 3/64, 1/16, 1/8, 1/4, 1/2.
    const int cb[7] = {0, N_PAIR / 64, N_PAIR / 16, N_PAIR / 8,
                       N_PAIR / 4, N_PAIR / 2, N_PAIR};
    for (int c = 0; c < 6; ++c) {
        int n_threads = (cb[c + 1] - cb[c]) / 2;   // 2 pairs per thread
        dim3 g((n_threads + BLK - 1) / BLK);
        gtsms_scatter_chunk<<<g, BLK, 0, stream>>>(pp, feat, m0, m1, mb0, mb1,
                                                   cb[c], n_threads);
        if (c < 5)
            gtsms_refresh_kernel<<<segGrid, BLK, 0, stream>>>(m0, m1, mb0, mb1);
    }
    gtsms_convert_rtne_kernel<<<segGrid, BLK, 0, stream>>>(m0, m1, mb0, mb1);
    gtsms_gather_kernel<<<gatherGrid, BLK, 0, stream>>>(pp, mb0, mb1, out);
}

// Round 16
// 669.993 us; speedup vs baseline: 1.3101x; 1.2807x over previous
//
#include <hip/hip_runtime.h>
#include <stdint.h>

#define N_ELEM 16777216
#define N_PAIR (N_ELEM / 2)
#define NUM_SEG 1000000
#define NBIN 128                 // bin = seg >> 13
#define SEG_PER_BIN 8192
#define ELEM_PER_WG 2048
#define NWG_A (N_ELEM / ELEM_PER_WG)     // 8192, exact
#define REC_PER_WG (2 * ELEM_PER_WG)     // 4096 records (2 tables)
#define NSPLIT 8
#define SLOTS_PER_SPLIT (NWG_A / NSPLIT) // 1024

typedef int   int4v   __attribute__((ext_vector_type(4)));
typedef float float2v __attribute__((ext_vector_type(2)));
typedef float float4v __attribute__((ext_vector_type(4)));
typedef unsigned int uint4v __attribute__((ext_vector_type(4)));

// Record pack: bits[15:0]=val16 (f32>>16 trunc bf16), bits[29:16]=table*8192+local
// (local = seg & 8191, table bit at 29 since 8192 = 1<<13).

// ---------------- radix path ----------------

// Phase A: per-WG bin sort of 4096 records, coalesced write + bin prefix table.
__global__ __launch_bounds__(256) void gtsms_phaseA(const int* __restrict__ pp,
                                                    const float* __restrict__ feat,
                                                    unsigned int* __restrict__ rec,
                                                    unsigned short* __restrict__ cnts) {
    __shared__ unsigned int hist[NBIN];
    __shared__ unsigned int basex[NBIN];
    __shared__ unsigned int recs[REC_PER_WG];
    const int wg = blockIdx.x, t = threadIdx.x;
    if (t < NBIN) hist[t] = 0;
    __syncthreads();

    const int ebase = wg * ELEM_PER_WG + t * 8;          // 8 elements/thread
    const int4v* pp4 = reinterpret_cast<const int4v*>(pp);
    const float4v* f4 = reinterpret_cast<const float4v*>(feat);
    int4v q0 = __builtin_nontemporal_load(pp4 + ebase / 2 + 0);
    int4v q1 = __builtin_nontemporal_load(pp4 + ebase / 2 + 1);
    int4v q2 = __builtin_nontemporal_load(pp4 + ebase / 2 + 2);
    int4v q3 = __builtin_nontemporal_load(pp4 + ebase / 2 + 3);
    float4v v0 = __builtin_nontemporal_load(f4 + ebase / 4 + 0);
    float4v v1 = __builtin_nontemporal_load(f4 + ebase / 4 + 1);

    int   id0[8], id1[8];
    unsigned int val[8];
    id0[0] = q0.x; id1[0] = q0.y; id0[1] = q0.z; id1[1] = q0.w;
    id0[2] = q1.x; id1[2] = q1.y; id0[3] = q1.z; id1[3] = q1.w;
    id0[4] = q2.x; id1[4] = q2.y; id0[5] = q2.z; id1[5] = q2.w;
    id0[6] = q3.x; id1[6] = q3.y; id0[7] = q3.z; id1[7] = q3.w;
    val[0] = __float_as_uint(v0.x) >> 16; val[1] = __float_as_uint(v0.y) >> 16;
    val[2] = __float_as_uint(v0.z) >> 16; val[3] = __float_as_uint(v0.w) >> 16;
    val[4] = __float_as_uint(v1.x) >> 16; val[5] = __float_as_uint(v1.y) >> 16;
    val[6] = __float_as_uint(v1.z) >> 16; val[7] = __float_as_uint(v1.w) >> 16;

    unsigned int rbin[16], rrank[16], rpk[16];
#pragma unroll
    for (int e = 0; e < 8; ++e) {
        unsigned int b0 = (unsigned int)id0[e] >> 13;
        unsigned int b1 = (unsigned int)id1[e] >> 13;
        rpk[2 * e]     = (((unsigned int)id0[e] & 8191u) << 16) | val[e];
        rpk[2 * e + 1] = (1u << 29) | (((unsigned int)id1[e] & 8191u) << 16) | val[e];
        rbin[2 * e] = b0;
        rbin[2 * e + 1] = b1;
        rrank[2 * e] = atomicAdd(&hist[b0], 1u);
        rrank[2 * e + 1] = atomicAdd(&hist[b1], 1u);
    }
    __syncthreads();

    if (t < 64) {   // exclusive scan of hist[128] by wave 0
        unsigned int a0 = hist[t], a1 = hist[t + 64];
        unsigned int s0 = a0, s1 = a1;
#pragma unroll
        for (int d = 1; d < 64; d <<= 1) {
            unsigned int n = __shfl_up(s0, d);
            if (t >= d) s0 += n;
        }
        unsigned int tot0 = __shfl(s0, 63);
#pragma unroll
        for (int d = 1; d < 64; d <<= 1) {
            unsigned int n = __shfl_up(s1, d);
            if (t >= d) s1 += n;
        }
        basex[t] = s0 - a0;
        basex[t + 64] = tot0 + s1 - a1;
    }
    __syncthreads();

#pragma unroll
    for (int r = 0; r < 16; ++r)
        recs[basex[rbin[r]] + rrank[r]] = rpk[r];
    __syncthreads();

    uint4v* ro = reinterpret_cast<uint4v*>(rec + (size_t)wg * REC_PER_WG);
#pragma unroll
    for (int k = 0; k < 4; ++k) {
        int q = t + 256 * k;
        uint4v w = { recs[4 * q], recs[4 * q + 1], recs[4 * q + 2], recs[4 * q + 3] };
        __builtin_nontemporal_store(w, ro + q);
    }
    if (t < NBIN) cnts[(size_t)wg * NBIN + t] = (unsigned short)basex[t];
}

// Phase B: per (bin,split) LDS max-table over its records; write bf16 partials.
__global__ __launch_bounds__(256) void gtsms_phaseB(const unsigned int* __restrict__ rec,
                                                    const unsigned short* __restrict__ cnts,
                                                    unsigned short* __restrict__ partials) {
    __shared__ unsigned int tab[2 * SEG_PER_BIN];   // 64 KB
    const int bin = blockIdx.x >> 3;
    const int split = blockIdx.x & 7;
    const int t = threadIdx.x;
    for (int i = t; i < 2 * SEG_PER_BIN; i += 256) tab[i] = 0u;
    __syncthreads();

    const int wave = t >> 6, lane = t & 63;
    const int sub = lane >> 4, sl = lane & 15;      // 4 sub-groups of 16 lanes
    const int slot0 = split * SLOTS_PER_SPLIT + wave * (SLOTS_PER_SPLIT / 4);
    for (int g = 0; g < SLOTS_PER_SPLIT / 16; ++g) {   // 64 groups x 4 slots
        int s = slot0 + g * 4 + sub;
        unsigned int b0 = cnts[(size_t)s * NBIN + bin];
        unsigned int e0 = (bin < NBIN - 1) ? cnts[(size_t)s * NBIN + bin + 1]
                                           : (unsigned int)REC_PER_WG;
        const unsigned int* rp = rec + (size_t)s * REC_PER_WG;
        for (unsigned int j = b0 + sl; j < e0; j += 16) {
            unsigned int r = rp[j];
            atomicMax(&tab[(r >> 16) & 0x3FFFu], r << 16);
        }
    }
    __syncthreads();
    unsigned short* po = partials + (size_t)(bin * NSPLIT + split) * (2 * SEG_PER_BIN);
    for (int i = t; i < 2 * SEG_PER_BIN; i += 256)
        po[i] = (unsigned short)(tab[i] >> 16);
}

// Merge 8 splits -> bf16 tables.
__global__ void gtsms_merge(const unsigned short* __restrict__ partials,
                            unsigned short* __restrict__ mb0,
                            unsigned short* __restrict__ mb1) {
    int seg = blockIdx.x * 256 + threadIdx.x;
    if (seg >= NUM_SEG) return;
    int bin = seg >> 13, local = seg & 8191;
    const unsigned short* p = partials + (size_t)bin * NSPLIT * (2 * SEG_PER_BIN);
    unsigned int u0 = 0, u1 = 0;
#pragma unroll
    for (int s = 0; s < NSPLIT; ++s) {
        u0 = max(u0, (unsigned int)p[s * (2 * SEG_PER_BIN) + local]);
        u1 = max(u1, (unsigned int)p[s * (2 * SEG_PER_BIN) + SEG_PER_BIN + local]);
    }
    mb0[seg] = (unsigned short)u0;
    mb1[seg] = (unsigned short)u1;
}

// Gather (R9-proven): plain table loads, 4 elements/thread.
__global__ void gtsms_gather_kernel(const int* __restrict__ pp,
                                    const unsigned short* __restrict__ mb0,
                                    const unsigned short* __restrict__ mb1,
                                    float* __restrict__ out) {
    int t = blockIdx.x * blockDim.x + threadIdx.x;
    if (t < N_PAIR / 2) {
        int p = 2 * t;
        int4v prA = __builtin_nontemporal_load(reinterpret_cast<const int4v*>(pp) + p);
        int4v prB = __builtin_nontemporal_load(reinterpret_cast<const int4v*>(pp) + p + 1);
        unsigned int a0 = mb0[prA.x];
        unsigned int b0 = mb1[prA.y];
        unsigned int a1 = mb0[prA.z];
        unsigned int b1 = mb1[prA.w];
        unsigned int a2 = mb0[prB.x];
        unsigned int b2 = mb1[prB.y];
        unsigned int a3 = mb0[prB.z];
        unsigned int b3 = mb1[prB.w];
        float4v o;
        o.x = __uint_as_float(a0 << 16) * __uint_as_float(b0 << 16);
        o.y = __uint_as_float(a1 << 16) * __uint_as_float(b1 << 16);
        o.z = __uint_as_float(a2 << 16) * __uint_as_float(b2 << 16);
        o.w = __uint_as_float(a3 << 16) * __uint_as_float(b3 << 16);
        __builtin_nontemporal_store(o, reinterpret_cast<float4v*>(out) + t);
    }
}

// ---------------- fallback (R9) path ----------------

__global__ void gtsms_zero_kernel(uint4v* __restrict__ ws, int n_vec4) {
    int i = blockIdx.x * blockDim.x + threadIdx.x;
    if (i < n_vec4) ws[i] = (uint4v){0u, 0u, 0u, 0u};
}

__global__ void gtsms_scatter_chunk(const int* __restrict__ pp,
                                    const float* __restrict__ feat,
                                    unsigned int* __restrict__ m0,
                                    unsigned int* __restrict__ m1,
                                    const unsigned short* __restrict__ mb0,
                                    const unsigned short* __restrict__ mb1,
                                    int base_pair, int n_threads) {
    int t = blockIdx.x * blockDim.x + threadIdx.x;
    if (t >= n_threads) return;
    int p = base_pair + 2 * t;
    int4v prA = __builtin_nontemporal_load(reinterpret_cast<const int4v*>(pp) + p);
    int4v prB = __builtin_nontemporal_load(reinterpret_cast<const int4v*>(pp) + p + 1);
    float2v fvA = __builtin_nontemporal_load(reinterpret_cast<const float2v*>(feat) + p);
    float2v fvB = __builtin_nontemporal_load(reinterpret_cast<const float2v*>(feat) + p + 1);
    unsigned int f0 = __float_as_uint(fvA.x);
    unsigned int f1 = __float_as_uint(fvA.y);
    unsigned int f2 = __float_as_uint(fvB.x);
    unsigned int f3 = __float_as_uint(fvB.y);
    unsigned int c0 = mb0[prA.x];
    unsigned int c1 = mb1[prA.y];
    unsigned int c2 = mb0[prA.z];
    unsigned int c3 = mb1[prA.w];
    unsigned int c4 = mb0[prB.x];
    unsigned int c5 = mb1[prB.y];
    unsigned int c6 = mb0[prB.z];
    unsigned int c7 = mb1[prB.w];
    if (f0 > (c0 << 16)) atomicMax(&m0[prA.x], f0);
    if (f0 > (c1 << 16)) atomicMax(&m1[prA.y], f0);
    if (f1 > (c2 << 16)) atomicMax(&m0[prA.z], f1);
    if (f1 > (c3 << 16)) atomicMax(&m1[prA.w], f1);
    if (f2 > (c4 << 16)) atomicMax(&m0[prB.x], f2);
    if (f2 > (c5 << 16)) atomicMax(&m1[prB.y], f2);
    if (f3 > (c6 << 16)) atomicMax(&m0[prB.z], f3);
    if (f3 > (c7 << 16)) atomicMax(&m1[prB.w], f3);
}

__global__ void gtsms_refresh_kernel(const unsigned int* __restrict__ m0,
                                     const unsigned int* __restrict__ m1,
                                     unsigned short* __restrict__ mb0,
                                     unsigned short* __restrict__ mb1) {
    int i = blockIdx.x * blockDim.x + threadIdx.x;
    if (i < NUM_SEG) {
        mb0[i] = (unsigned short)(m0[i] >> 16);
        mb1[i] = (unsigned short)(m1[i] >> 16);
    }
}

__global__ void gtsms_convert_rtne_kernel(const unsigned int* __restrict__ m0,
                                          const unsigned int* __restrict__ m1,
                                          unsigned short* __restrict__ mb0,
                                          unsigned short* __restrict__ mb1) {
    int i = blockIdx.x * blockDim.x + threadIdx.x;
    if (i < NUM_SEG) {
        unsigned int u0 = m0[i];
        unsigned int u1 = m1[i];
        mb0[i] = (unsigned short)((u0 + 0x7FFFu + ((u0 >> 16) & 1u)) >> 16);
        mb1[i] = (unsigned short)((u1 + 0x7FFFu + ((u1 >> 16) & 1u)) >> 16);
    }
}

// ---------------- launch ----------------

extern "C" void kernel_launch(void* const* d_in, const int* in_sizes, int n_in,
                              void* d_out, int out_size, void* d_ws, size_t ws_size,
                              hipStream_t stream) {
    const int* pp = (const int*)d_in[0];
    const float* feat = (const float*)d_in[1];
    float* out = (float*)d_out;

    const int BLK = 256;
    dim3 gatherGrid((N_PAIR / 2 + BLK - 1) / BLK);

    const size_t O_REC = 0;
    const size_t O_CNT = O_REC + (size_t)NWG_A * REC_PER_WG * 4;          // 134,217,728
    const size_t O_PART = O_CNT + (size_t)NWG_A * NBIN * 2;               // +2 MB
    const size_t O_TAB = O_PART + (size_t)NBIN * NSPLIT * 2 * SEG_PER_BIN * 2; // +32 MB
    const size_t NEED = O_TAB + (size_t)2 * NUM_SEG * 2;                  // +4 MB

    if (ws_size >= NEED) {
        unsigned int* rec = (unsigned int*)((char*)d_ws + O_REC);
        unsigned short* cnts = (unsigned short*)((char*)d_ws + O_CNT);
        unsigned short* partials = (unsigned short*)((char*)d_ws + O_PART);
        unsigned short* mb0 = (unsigned short*)((char*)d_ws + O_TAB);
        unsigned short* mb1 = mb0 + NUM_SEG;

        gtsms_phaseA<<<NWG_A, BLK, 0, stream>>>(pp, feat, rec, cnts);
        gtsms_phaseB<<<NBIN * NSPLIT, BLK, 0, stream>>>(rec, cnts, partials);
        gtsms_merge<<<(NUM_SEG + BLK - 1) / BLK, BLK, 0, stream>>>(partials, mb0, mb1);
        gtsms_gather_kernel<<<gatherGrid, BLK, 0, stream>>>(pp, mb0, mb1, out);
    } else {
        unsigned int* m0 = (unsigned int*)d_ws;
        unsigned int* m1 = m0 + NUM_SEG;
        unsigned short* mb0 = (unsigned short*)(m1 + NUM_SEG);
        unsigned short* mb1 = mb0 + NUM_SEG;

        dim3 segGrid((NUM_SEG + BLK - 1) / BLK);
        int zero_vec4 = (3 * NUM_SEG) / 4;
        dim3 zeroGrid((zero_vec4 + BLK - 1) / BLK);
        gtsms_zero_kernel<<<zeroGrid, BLK, 0, stream>>>((uint4v*)d_ws, zero_vec4);

        const int cb[7] = {0, N_PAIR / 64, N_PAIR / 16, N_PAIR / 8,
                           N_PAIR / 4, N_PAIR / 2, N_PAIR};
        for (int c = 0; c < 6; ++c) {
            int n_threads = (cb[c + 1] - cb[c]) / 2;
            dim3 g((n_threads + BLK - 1) / BLK);
            gtsms_scatter_chunk<<<g, BLK, 0, stream>>>(pp, feat, m0, m1, mb0, mb1,
                                                       cb[c], n_threads);
            if (c < 5)
                gtsms_refresh_kernel<<<segGrid, BLK, 0, stream>>>(m0, m1, mb0, mb1);
        }
        gtsms_convert_rtne_kernel<<<segGrid, BLK, 0, stream>>>(m0, m1, mb0, mb1);
        gtsms_gather_kernel<<<gatherGrid, BLK, 0, stream>>>(pp, mb0, mb1, out);
    }
}

// Round 18
// 601.736 us; speedup vs baseline: 1.4587x; 1.1134x over previous
//
#include <hip/hip_runtime.h>
#include <stdint.h>

#define N_ELEM 16777216
#define N_PAIR (N_ELEM / 2)
#define NUM_SEG 1000000
#define NBIN 256                 // bin = (table<<7) | (seg>>13)
#define SEG_PER_BIN 8192
#define ELEM_PER_WG 2048
#define NWG_A (N_ELEM / ELEM_PER_WG)     // 8192, exact
#define REC_PER_WG (2 * ELEM_PER_WG)     // 4096 records (2 tables)
#define NSPLIT 4
#define SLOTS_PER_SPLIT (NWG_A / NSPLIT) // 2048

typedef int   int4v   __attribute__((ext_vector_type(4)));
typedef float float2v __attribute__((ext_vector_type(2)));
typedef float float4v __attribute__((ext_vector_type(4)));
typedef unsigned int uint4v __attribute__((ext_vector_type(4)));

// Record pack: bits[15:0]=val16 (f32>>16 trunc bf16), bits[28:16]=local
// (local = seg & 8191). Table is encoded in the bin index (bit 7).

// ---------------- radix path ----------------

// Phase A: per-WG 256-bin sort of 4096 records, coalesced write + prefix table.
__global__ __launch_bounds__(256) void gtsms_phaseA(const int* __restrict__ pp,
                                                    const float* __restrict__ feat,
                                                    unsigned int* __restrict__ rec,
                                                    unsigned short* __restrict__ cnts) {
    __shared__ unsigned int hist[NBIN];
    __shared__ unsigned int basex[NBIN];
    __shared__ unsigned int recs[REC_PER_WG];
    const int wg = blockIdx.x, t = threadIdx.x;
    hist[t] = 0;
    __syncthreads();

    const int ebase = wg * ELEM_PER_WG + t * 8;          // 8 elements/thread
    const int4v* pp4 = reinterpret_cast<const int4v*>(pp);
    const float4v* f4 = reinterpret_cast<const float4v*>(feat);
    int4v q0 = __builtin_nontemporal_load(pp4 + ebase / 2 + 0);
    int4v q1 = __builtin_nontemporal_load(pp4 + ebase / 2 + 1);
    int4v q2 = __builtin_nontemporal_load(pp4 + ebase / 2 + 2);
    int4v q3 = __builtin_nontemporal_load(pp4 + ebase / 2 + 3);
    float4v v0 = __builtin_nontemporal_load(f4 + ebase / 4 + 0);
    float4v v1 = __builtin_nontemporal_load(f4 + ebase / 4 + 1);

    int   id0[8], id1[8];
    unsigned int val[8];
    id0[0] = q0.x; id1[0] = q0.y; id0[1] = q0.z; id1[1] = q0.w;
    id0[2] = q1.x; id1[2] = q1.y; id0[3] = q1.z; id1[3] = q1.w;
    id0[4] = q2.x; id1[4] = q2.y; id0[5] = q2.z; id1[5] = q2.w;
    id0[6] = q3.x; id1[6] = q3.y; id0[7] = q3.z; id1[7] = q3.w;
    val[0] = __float_as_uint(v0.x) >> 16; val[1] = __float_as_uint(v0.y) >> 16;
    val[2] = __float_as_uint(v0.z) >> 16; val[3] = __float_as_uint(v0.w) >> 16;
    val[4] = __float_as_uint(v1.x) >> 16; val[5] = __float_as_uint(v1.y) >> 16;
    val[6] = __float_as_uint(v1.z) >> 16; val[7] = __float_as_uint(v1.w) >> 16;

    unsigned int rbin[16], rrank[16], rpk[16];
#pragma unroll
    for (int e = 0; e < 8; ++e) {
        unsigned int b0 = (unsigned int)id0[e] >> 13;          // table0: bins 0..127
        unsigned int b1 = 128u + ((unsigned int)id1[e] >> 13); // table1: bins 128..255
        rpk[2 * e]     = (((unsigned int)id0[e] & 8191u) << 16) | val[e];
        rpk[2 * e + 1] = (((unsigned int)id1[e] & 8191u) << 16) | val[e];
        rbin[2 * e] = b0;
        rbin[2 * e + 1] = b1;
        rrank[2 * e] = atomicAdd(&hist[b0], 1u);
        rrank[2 * e + 1] = atomicAdd(&hist[b1], 1u);
    }
    __syncthreads();

    if (t < 64) {   // exclusive scan of hist[256]: wave 0, 4 chunks with carry
        unsigned int carry = 0;
#pragma unroll
        for (int blk = 0; blk < 4; ++blk) {
            unsigned int a = hist[blk * 64 + t];
            unsigned int s = a;
#pragma unroll
            for (int d = 1; d < 64; d <<= 1) {
                unsigned int n = __shfl_up(s, d);
                if (t >= d) s += n;
            }
            basex[blk * 64 + t] = carry + s - a;
            carry += __shfl(s, 63);
        }
    }
    __syncthreads();

#pragma unroll
    for (int r = 0; r < 16; ++r)
        recs[basex[rbin[r]] + rrank[r]] = rpk[r];
    __syncthreads();

    uint4v* ro = reinterpret_cast<uint4v*>(rec + (size_t)wg * REC_PER_WG);
#pragma unroll
    for (int k = 0; k < 4; ++k) {
        int q = t + 256 * k;
        uint4v w = { recs[4 * q], recs[4 * q + 1], recs[4 * q + 2], recs[4 * q + 3] };
        __builtin_nontemporal_store(w, ro + q);
    }
    cnts[(size_t)wg * NBIN + t] = (unsigned short)basex[t];
}

// Phase B: per (bin,split) 32 KB LDS max-table; 5 WGs/CU (was 2 at 64 KB).
__global__ __launch_bounds__(256) void gtsms_phaseB(const unsigned int* __restrict__ rec,
                                                    const unsigned short* __restrict__ cnts,
                                                    unsigned short* __restrict__ partials) {
    __shared__ unsigned int tab[SEG_PER_BIN];   // 32 KB
    const int bin = blockIdx.x >> 2;            // 0..255 (includes table bit)
    const int split = blockIdx.x & 3;
    const int t = threadIdx.x;
    for (int i = t; i < SEG_PER_BIN; i += 256) tab[i] = 0u;
    __syncthreads();

    const int wave = t >> 6, lane = t & 63;
    const int sub = lane >> 4, sl = lane & 15;      // 4 sub-groups of 16 lanes
    const int slot0 = split * SLOTS_PER_SPLIT + wave * (SLOTS_PER_SPLIT / 4);
    for (int g = 0; g < SLOTS_PER_SPLIT / 16; ++g) {   // 128 groups x 4 slots
        int s = slot0 + g * 4 + sub;
        unsigned int b0 = cnts[(size_t)s * NBIN + bin];
        unsigned int e0 = (bin < NBIN - 1) ? cnts[(size_t)s * NBIN + bin + 1]
                                           : (unsigned int)REC_PER_WG;
        const unsigned int* rp = rec + (size_t)s * REC_PER_WG;
        for (unsigned int j = b0 + sl; j < e0; j += 16) {
            unsigned int r = rp[j];
            atomicMax(&tab[(r >> 16) & 0x1FFFu], r << 16);
        }
    }
    __syncthreads();
    unsigned short* po = partials + (size_t)(bin * NSPLIT + split) * SEG_PER_BIN;
    for (int i = t; i < SEG_PER_BIN; i += 256)
        po[i] = (unsigned short)(tab[i] >> 16);
}

// Merge 4 splits -> bf16 tables.
__global__ void gtsms_merge(const unsigned short* __restrict__ partials,
                            unsigned short* __restrict__ mb0,
                            unsigned short* __restrict__ mb1) {
    int seg = blockIdx.x * 256 + threadIdx.x;
    if (seg >= NUM_SEG) return;
    int b = seg >> 13, local = seg & 8191;
    const unsigned short* p0 = partials + (size_t)(b * NSPLIT) * SEG_PER_BIN;
    const unsigned short* p1 = partials + (size_t)((128 + b) * NSPLIT) * SEG_PER_BIN;
    unsigned int u0 = 0, u1 = 0;
#pragma unroll
    for (int s = 0; s < NSPLIT; ++s) {
        u0 = max(u0, (unsigned int)p0[s * SEG_PER_BIN + local]);
        u1 = max(u1, (unsigned int)p1[s * SEG_PER_BIN + local]);
    }
    mb0[seg] = (unsigned short)u0;
    mb1[seg] = (unsigned short)u1;
}

// Gather (R9-proven): plain table loads, 4 elements/thread.
__global__ void gtsms_gather_kernel(const int* __restrict__ pp,
                                    const unsigned short* __restrict__ mb0,
                                    const unsigned short* __restrict__ mb1,
                                    float* __restrict__ out) {
    int t = blockIdx.x * blockDim.x + threadIdx.x;
    if (t < N_PAIR / 2) {
        int p = 2 * t;
        int4v prA = __builtin_nontemporal_load(reinterpret_cast<const int4v*>(pp) + p);
        int4v prB = __builtin_nontemporal_load(reinterpret_cast<const int4v*>(pp) + p + 1);
        unsigned int a0 = mb0[prA.x];
        unsigned int b0 = mb1[prA.y];
        unsigned int a1 = mb0[prA.z];
        unsigned int b1 = mb1[prA.w];
        unsigned int a2 = mb0[prB.x];
        unsigned int b2 = mb1[prB.y];
        unsigned int a3 = mb0[prB.z];
        unsigned int b3 = mb1[prB.w];
        float4v o;
        o.x = __uint_as_float(a0 << 16) * __uint_as_float(b0 << 16);
        o.y = __uint_as_float(a1 << 16) * __uint_as_float(b1 << 16);
        o.z = __uint_as_float(a2 << 16) * __uint_as_float(b2 << 16);
        o.w = __uint_as_float(a3 << 16) * __uint_as_float(b3 << 16);
        __builtin_nontemporal_store(o, reinterpret_cast<float4v*>(out) + t);
    }
}

// ---------------- fallback (R9) path ----------------

__global__ void gtsms_zero_kernel(uint4v* __restrict__ ws, int n_vec4) {
    int i = blockIdx.x * blockDim.x + threadIdx.x;
    if (i < n_vec4) ws[i] = (uint4v){0u, 0u, 0u, 0u};
}

__global__ void gtsms_scatter_chunk(const int* __restrict__ pp,
                                    const float* __restrict__ feat,
                                    unsigned int* __restrict__ m0,
                                    unsigned int* __restrict__ m1,
                                    const unsigned short* __restrict__ mb0,
                                    const unsigned short* __restrict__ mb1,
                                    int base_pair, int n_threads) {
    int t = blockIdx.x * blockDim.x + threadIdx.x;
    if (t >= n_threads) return;
    int p = base_pair + 2 * t;
    int4v prA = __builtin_nontemporal_load(reinterpret_cast<const int4v*>(pp) + p);
    int4v prB = __builtin_nontemporal_load(reinterpret_cast<const int4v*>(pp) + p + 1);
    float2v fvA = __builtin_nontemporal_load(reinterpret_cast<const float2v*>(feat) + p);
    float2v fvB = __builtin_nontemporal_load(reinterpret_cast<const float2v*>(feat) + p + 1);
    unsigned int f0 = __float_as_uint(fvA.x);
    unsigned int f1 = __float_as_uint(fvA.y);
    unsigned int f2 = __float_as_uint(fvB.x);
    unsigned int f3 = __float_as_uint(fvB.y);
    unsigned int c0 = mb0[prA.x];
    unsigned int c1 = mb1[prA.y];
    unsigned int c2 = mb0[prA.z];
    unsigned int c3 = mb1[prA.w];
    unsigned int c4 = mb0[prB.x];
    unsigned int c5 = mb1[prB.y];
    unsigned int c6 = mb0[prB.z];
    unsigned int c7 = mb1[prB.w];
    if (f0 > (c0 << 16)) atomicMax(&m0[prA.x], f0);
    if (f0 > (c1 << 16)) atomicMax(&m1[prA.y], f0);
    if (f1 > (c2 << 16)) atomicMax(&m0[prA.z], f1);
    if (f1 > (c3 << 16)) atomicMax(&m1[prA.w], f1);
    if (f2 > (c4 << 16)) atomicMax(&m0[prB.x], f2);
    if (f2 > (c5 << 16)) atomicMax(&m1[prB.y], f2);
    if (f3 > (c6 << 16)) atomicMax(&m0[prB.z], f3);
    if (f3 > (c7 << 16)) atomicMax(&m1[prB.w], f3);
}

__global__ void gtsms_refresh_kernel(const unsigned int* __restrict__ m0,
                                     const unsigned int* __restrict__ m1,
                                     unsigned short* __restrict__ mb0,
                                     unsigned short* __restrict__ mb1) {
    int i = blockIdx.x * blockDim.x + threadIdx.x;
    if (i < NUM_SEG) {
        mb0[i] = (unsigned short)(m0[i] >> 16);
        mb1[i] = (unsigned short)(m1[i] >> 16);
    }
}

__global__ void gtsms_convert_rtne_kernel(const unsigned int* __restrict__ m0,
                                          const unsigned int* __restrict__ m1,
                                          unsigned short* __restrict__ mb0,
                                          unsigned short* __restrict__ mb1) {
    int i = blockIdx.x * blockDim.x + threadIdx.x;
    if (i < NUM_SEG) {
        unsigned int u0 = m0[i];
        unsigned int u1 = m1[i];
        mb0[i] = (unsigned short)((u0 + 0x7FFFu + ((u0 >> 16) & 1u)) >> 16);
        mb1[i] = (unsigned short)((u1 + 0x7FFFu + ((u1 >> 16) & 1u)) >> 16);
    }
}

// ---------------- launch ----------------

extern "C" void kernel_launch(void* const* d_in, const int* in_sizes, int n_in,
                              void* d_out, int out_size, void* d_ws, size_t ws_size,
                              hipStream_t stream) {
    const int* pp = (const int*)d_in[0];
    const float* feat = (const float*)d_in[1];
    float* out = (float*)d_out;

    const int BLK = 256;
    dim3 gatherGrid((N_PAIR / 2 + BLK - 1) / BLK);

    const size_t O_REC = 0;
    const size_t O_CNT = O_REC + (size_t)NWG_A * REC_PER_WG * 4;            // 134,217,728
    const size_t O_PART = O_CNT + (size_t)NWG_A * NBIN * 2;                 // +4 MB
    const size_t O_TAB = O_PART + (size_t)NBIN * NSPLIT * SEG_PER_BIN * 2;  // +16 MB
    const size_t NEED = O_TAB + (size_t)2 * NUM_SEG * 2;                    // +4 MB  => ~152 MB

    if (ws_size >= NEED) {
        unsigned int* rec = (unsigned int*)((char*)d_ws + O_REC);
        unsigned short* cnts = (unsigned short*)((char*)d_ws + O_CNT);
        unsigned short* partials = (unsigned short*)((char*)d_ws + O_PART);
        unsigned short* mb0 = (unsigned short*)((char*)d_ws + O_TAB);
        unsigned short* mb1 = mb0 + NUM_SEG;

        gtsms_phaseA<<<NWG_A, BLK, 0, stream>>>(pp, feat, rec, cnts);
        gtsms_phaseB<<<NBIN * NSPLIT, BLK, 0, stream>>>(rec, cnts, partials);
        gtsms_merge<<<(NUM_SEG + BLK - 1) / BLK, BLK, 0, stream>>>(partials, mb0, mb1);
        gtsms_gather_kernel<<<gatherGrid, BLK, 0, stream>>>(pp, mb0, mb1, out);
    } else {
        unsigned int* m0 = (unsigned int*)d_ws;
        unsigned int* m1 = m0 + NUM_SEG;
        unsigned short* mb0 = (unsigned short*)(m1 + NUM_SEG);
        unsigned short* mb1 = mb0 + NUM_SEG;

        dim3 segGrid((NUM_SEG + BLK - 1) / BLK);
        int zero_vec4 = (3 * NUM_SEG) / 4;
        dim3 zeroGrid((zero_vec4 + BLK - 1) / BLK);
        gtsms_zero_kernel<<<zeroGrid, BLK, 0, stream>>>((uint4v*)d_ws, zero_vec4);

        const int cb[7] = {0, N_PAIR / 64, N_PAIR / 16, N_PAIR / 8,
                           N_PAIR / 4, N_PAIR / 2, N_PAIR};
        for (int c = 0; c < 6; ++c) {
            int n_threads = (cb[c + 1] - cb[c]) / 2;
            dim3 g((n_threads + BLK - 1) / BLK);
            gtsms_scatter_chunk<<<g, BLK, 0, stream>>>(pp, feat, m0, m1, mb0, mb1,
                                                       cb[c], n_threads);
            if (c < 5)
                gtsms_refresh_kernel<<<segGrid, BLK, 0, stream>>>(m0, m1, mb0, mb1);
        }
        gtsms_convert_rtne_kernel<<<segGrid, BLK, 0, stream>>>(m0, m1, mb0, mb1);
        gtsms_gather_kernel<<<gatherGrid, BLK, 0, stream>>>(pp, mb0, mb1, out);
    }
}